// Round 1
// baseline (118203.406 us; speedup 1.0000x reference)
//
#include <hip/hip_runtime.h>

// 2-layer LSTM encoder, B=128 T=512 E=256 H=1024.
// Design (round 1):
//  - per timestep: 2 dispatches (layer0, layer1), 1024 kernel nodes total.
//  - GEMM: split-bf16 (hi/lo) via mfma_f32_16x16x32_bf16, 3 products -> ~fp32 precision.
//  - split-K x8: 512 blocks = 64 N-tiles (16 units x 4 gates) x 8 K-slices.
//    Partial z -> ws; last block per tile (atomic counter) reduces + bias + LSTM cell.
//  - h states stored as bf16 hi/lo pairs (ping-pong buffers); c states fp32 in-place.
//  - W converted fp32->bf16 hi/lo on the fly while staging into LDS (same cache bytes).

namespace {
constexpr int Tt = 512, Ee = 256, Hh = 1024, G4H = 4096;
constexpr int NTILE = 64;            // N tiles of 16 units (x4 gates = 64 cols)
constexpr int KSPLIT = 8;
constexpr int NBLK = NTILE * KSPLIT; // 512 blocks
constexpr int THREADS = 256;         // 4 waves; wave = 32 rows (2 M-frags) x 64 cols
}

typedef __bf16 bf16x8 __attribute__((ext_vector_type(8)));
typedef float f32x4 __attribute__((ext_vector_type(4)));
typedef float f32x4v __attribute__((ext_vector_type(4)));
typedef unsigned short u16x4 __attribute__((ext_vector_type(4)));
typedef unsigned short u16x8 __attribute__((ext_vector_type(8)));

__device__ __forceinline__ unsigned short f2bf(float f) {
  unsigned u = __float_as_uint(f);
  u += 0x7fffu + ((u >> 16) & 1u);   // RNE; inputs are finite
  return (unsigned short)(u >> 16);
}
__device__ __forceinline__ float bf2f(unsigned short h) {
  return __uint_as_float(((unsigned)h) << 16);
}
__device__ __forceinline__ float sigm(float x) { return 1.0f / (1.0f + __expf(-x)); }
__device__ __forceinline__ float tanh_f(float x) {
  float e = __expf(-2.0f * fabsf(x));
  float r = (1.0f - e) / (1.0f + e);
  return x >= 0.0f ? r : -r;
}

__global__ __launch_bounds__(THREADS) void lstm_step_kernel(
    int layer, int t,
    const int* __restrict__ ib, const int* __restrict__ lens,
    const float* __restrict__ emb,
    const float* __restrict__ W, const float* __restrict__ bias,
    const unsigned short* __restrict__ a1hi, const unsigned short* __restrict__ a1lo, // L1: h0_new
    const unsigned short* __restrict__ a2hi, const unsigned short* __restrict__ a2lo, // h_in (L0:h0, L1:h1)
    unsigned short* __restrict__ hohi, unsigned short* __restrict__ holo,             // h_out
    float* __restrict__ cst,
    int* counters, float* partials)
{
  const int tid = threadIdx.x;
  const int ntile = blockIdx.x & (NTILE - 1);
  const int ks = blockIdx.x >> 6;           // 0..7
  const int u0 = ntile * 16;
  const int Kslice = layer ? 256 : 160;     // 2048/8, 1280/8
  const int nkt = layer ? 8 : 5;            // k-tiles of 32 per slice
  const int kbase = ks * Kslice;

  // LDS: stride 36 elements (72B) -> 8B-aligned b64 frag reads, banks spread
  __shared__ unsigned short Ah[128][36], Al[128][36];
  __shared__ unsigned short Bh[64][36], Bl[64][36];
  __shared__ int s_last;

  const int w = tid >> 6;                   // wave 0..3
  const int lane = tid & 63;
  const int lr = lane & 15;
  const int lg4 = ((lane >> 4) & 3) * 4;    // k-group offset {0,4,8,12}

  f32x4 acc[2][4];
  #pragma unroll
  for (int m = 0; m < 2; ++m)
    #pragma unroll
    for (int g = 0; g < 4; ++g)
      acc[m][g] = (f32x4){0.f, 0.f, 0.f, 0.f};

  // staging assignments
  const int ar = tid >> 1;                  // A row 0..127
  const int akh = (tid & 1) * 16;           // A k half (16 elements, 4 quads)
  const int bc = tid & 63;                  // B col-in-tile 0..63 (gate-major)
  const int bg = bc >> 4;
  const int bcol = bg * Hh + u0 + (bc & 15);
  const int bkq = (tid >> 6) * 8;           // B k chunk of 8

  for (int kt = 0; kt < nkt; ++kt) {
    const int k0 = kt * 32;
    // ---- stage A tile (rows x 32k) : hi/lo bf16 ----
    #pragma unroll
    for (int q = 0; q < 4; ++q) {
      const int kl = akh + q * 4;
      const int kg = kbase + k0 + kl;
      u16x4 vh, vl;
      if (layer == 0 && kg < Ee) {          // embedding gather + convert
        const int erow = ib[ar * Tt + t];
        f32x4v v = *(const f32x4v*)&emb[erow * Ee + kg];
        #pragma unroll
        for (int j = 0; j < 4; ++j) {
          unsigned short h = f2bf(v[j]);
          vh[j] = h; vl[j] = f2bf(v[j] - bf2f(h));
        }
      } else {
        const unsigned short *ph, *pl;
        if (layer == 0)      { ph = &a2hi[ar * Hh + (kg - Ee)]; pl = &a2lo[ar * Hh + (kg - Ee)]; }
        else if (kg < Hh)    { ph = &a1hi[ar * Hh + kg];        pl = &a1lo[ar * Hh + kg]; }
        else                 { ph = &a2hi[ar * Hh + (kg - Hh)]; pl = &a2lo[ar * Hh + (kg - Hh)]; }
        vh = *(const u16x4*)ph; vl = *(const u16x4*)pl;
      }
      *(u16x4*)&Ah[ar][kl] = vh;
      *(u16x4*)&Al[ar][kl] = vl;
    }
    // ---- stage B tile (32k x 64cols, transposed [col][k]) : fp32 -> hi/lo ----
    {
      u16x4 vh0, vl0, vh1, vl1;
      #pragma unroll
      for (int j = 0; j < 8; ++j) {
        const int kg = kbase + k0 + bkq + j;
        const float f = W[(size_t)kg * G4H + bcol];
        const unsigned short h = f2bf(f);
        const unsigned short l = f2bf(f - bf2f(h));
        if (j < 4) { vh0[j] = h; vl0[j] = l; } else { vh1[j-4] = h; vl1[j-4] = l; }
      }
      *(u16x4*)&Bh[bc][bkq]     = vh0;
      *(u16x4*)&Bl[bc][bkq]     = vl0;
      *(u16x4*)&Bh[bc][bkq + 4] = vh1;
      *(u16x4*)&Bl[bc][bkq + 4] = vl1;
    }
    __syncthreads();
    // ---- fragments + MFMA (A: row=l&15, k=4*(l>>4)+(j&3)+16*(j>>2)) ----
    bf16x8 ah[2], al[2];
    #pragma unroll
    for (int m = 0; m < 2; ++m) {
      const int arow = w * 32 + m * 16 + lr;
      u16x8 hi8 = __builtin_shufflevector(*(const u16x4*)&Ah[arow][lg4],
                                          *(const u16x4*)&Ah[arow][16 + lg4], 0,1,2,3,4,5,6,7);
      u16x8 lo8 = __builtin_shufflevector(*(const u16x4*)&Al[arow][lg4],
                                          *(const u16x4*)&Al[arow][16 + lg4], 0,1,2,3,4,5,6,7);
      ah[m] = __builtin_bit_cast(bf16x8, hi8);
      al[m] = __builtin_bit_cast(bf16x8, lo8);
    }
    #pragma unroll
    for (int g = 0; g < 4; ++g) {
      const int bcc = g * 16 + lr;
      u16x8 bhi8 = __builtin_shufflevector(*(const u16x4*)&Bh[bcc][lg4],
                                           *(const u16x4*)&Bh[bcc][16 + lg4], 0,1,2,3,4,5,6,7);
      u16x8 blo8 = __builtin_shufflevector(*(const u16x4*)&Bl[bcc][lg4],
                                           *(const u16x4*)&Bl[bcc][16 + lg4], 0,1,2,3,4,5,6,7);
      bf16x8 bh = __builtin_bit_cast(bf16x8, bhi8);
      bf16x8 bl = __builtin_bit_cast(bf16x8, blo8);
      #pragma unroll
      for (int m = 0; m < 2; ++m) {
        acc[m][g] = __builtin_amdgcn_mfma_f32_16x16x32_bf16(ah[m], bh, acc[m][g], 0, 0, 0);
        acc[m][g] = __builtin_amdgcn_mfma_f32_16x16x32_bf16(ah[m], bl, acc[m][g], 0, 0, 0);
        acc[m][g] = __builtin_amdgcn_mfma_f32_16x16x32_bf16(al[m], bh, acc[m][g], 0, 0, 0);
      }
    }
    __syncthreads();
  }

  // ---- write partial z:  [ntile][ks][row 128][gate 4][unit 16] ----
  {
    float* pbase = &partials[(((size_t)ntile * KSPLIT + ks) * 128) * 64];
    #pragma unroll
    for (int g = 0; g < 4; ++g)
      #pragma unroll
      for (int m = 0; m < 2; ++m)
        #pragma unroll
        for (int rr = 0; rr < 4; ++rr) {
          const int row = w * 32 + m * 16 + lg4 + rr;  // C/D: row = 4*(l>>4)+reg
          pbase[((size_t)row * 4 + g) * 16 + lr] = acc[m][g][rr];
        }
  }
  __threadfence();
  __syncthreads();
  if (tid == 0) {
    const int cidx = (t * 2 + layer) * NTILE + ntile;
    s_last = (atomicAdd(&counters[cidx], 1) == KSPLIT - 1);
  }
  __syncthreads();
  if (!s_last) return;
  __threadfence();  // acquire: other slices' partials

  // ---- reduce + bias + LSTM cell (16 units x 128 rows) ----
  for (int it = 0; it < 8; ++it) {
    const int idx = it * THREADS + tid;   // 0..2047
    const int r = idx & 127;
    const int uu = idx >> 7;              // 0..15
    const int ug = u0 + uu;
    float z[4];
    #pragma unroll
    for (int g = 0; g < 4; ++g) {
      float s = bias[g * Hh + ug];
      #pragma unroll
      for (int p = 0; p < KSPLIT; ++p)
        s += partials[(((size_t)ntile * KSPLIT + p) * 128 + r) * 64 + g * 16 + uu];
      z[g] = s;
    }
    const bool mask = t < lens[r];
    unsigned short hh, hl;
    if (mask) {
      const float cold = cst[r * Hh + ug];
      const float nc = cold * sigm(z[2] + 1.0f) + sigm(z[0]) * tanh_f(z[1]);
      const float nh = tanh_f(nc) * sigm(z[3]);
      cst[r * Hh + ug] = nc;
      hh = f2bf(nh);
      hl = f2bf(nh - bf2f(hh));
    } else {
      hh = a2hi[r * Hh + ug];
      hl = a2lo[r * Hh + ug];
    }
    hohi[r * Hh + ug] = hh;
    holo[r * Hh + ug] = hl;
  }
}

__global__ void finalize_kernel(const unsigned short* __restrict__ hi,
                                const unsigned short* __restrict__ lo,
                                float* __restrict__ out) {
  const int i = blockIdx.x * 256 + threadIdx.x;
  out[i] = bf2f(hi[i]) + bf2f(lo[i]);
}

extern "C" void kernel_launch(void* const* d_in, const int* in_sizes, int n_in,
                              void* d_out, int out_size, void* d_ws, size_t ws_size,
                              hipStream_t stream) {
  const int*   ib   = (const int*)d_in[0];
  const int*   lens = (const int*)d_in[1];
  const float* emb  = (const float*)d_in[2];
  const float* W0   = (const float*)d_in[3];
  const float* b0   = (const float*)d_in[4];
  const float* W1   = (const float*)d_in[5];
  const float* b1   = (const float*)d_in[6];
  (void)in_sizes; (void)n_in; (void)out_size; (void)ws_size;

  char* ws = (char*)d_ws;
  size_t off = 0;
  auto alloc = [&](size_t bytes) { char* p = ws + off; off += bytes; return p; };
  const size_t HN = 128 * 1024;
  float* c0 = (float*)alloc(HN * 4);
  float* c1 = (float*)alloc(HN * 4);
  unsigned short *h0hi[2], *h0lo[2], *h1hi[2], *h1lo[2];
  for (int p = 0; p < 2; ++p) {
    h0hi[p] = (unsigned short*)alloc(HN * 2);
    h0lo[p] = (unsigned short*)alloc(HN * 2);
  }
  for (int p = 0; p < 2; ++p) {
    h1hi[p] = (unsigned short*)alloc(HN * 2);
    h1lo[p] = (unsigned short*)alloc(HN * 2);
  }
  int* counters = (int*)alloc((size_t)Tt * 2 * NTILE * 4);
  const size_t zero_bytes = off;                       // states + counters
  float* partials = (float*)alloc((size_t)NTILE * KSPLIT * 128 * 64 * 4);

  hipMemsetAsync(d_ws, 0, zero_bytes, stream);

  for (int t = 0; t < Tt; ++t) {
    const int p = t & 1, q = 1 - p;
    // layer 0: A = [emb(x_t) ; h0_in(p)] -> writes h0(q), c0
    lstm_step_kernel<<<NBLK, THREADS, 0, stream>>>(
        0, t, ib, lens, emb, W0, b0,
        h0hi[p], h0lo[p],            // a1 unused for layer 0
        h0hi[p], h0lo[p],            // a2 = h0_in
        h0hi[q], h0lo[q], c0, counters, partials);
    // layer 1: A = [h0_new(q) ; h1_in(p)] -> writes h1(q), c1
    lstm_step_kernel<<<NBLK, THREADS, 0, stream>>>(
        1, t, ib, lens, emb, W1, b1,
        h0hi[q], h0lo[q],            // a1 = h0_new
        h1hi[p], h1lo[p],            // a2 = h1_in
        h1hi[q], h1lo[q], c1, counters, partials);
  }
  // t=511 (odd) wrote parity 0
  finalize_kernel<<<(int)(HN / 256), 256, 0, stream>>>(h1hi[0], h1lo[0], (float*)d_out);
}

// Round 2
// 27346.994 us; speedup vs baseline: 4.3224x; 4.3224x over previous
//
#include <hip/hip_runtime.h>

// ---------------------------------------------------------------------------
// 2-layer LSTM encoder, B=128 T=512 E=256 H=1024 (round 2).
// Persistent kernel, 1 grid-sync per timestep. Per phase p:
//   L0-blocks (128): z0 = [x_p ; h0(p-1)] @ W0 ; cell -> h0(p), c0
//   L1-blocks (128): z1 = [h0(p-1) ; h1(p-2)] @ W1 ; cell -> h1(p-1), c1, out
// Split-bf16 (hi/lo) x3 MFMA products for ~fp32 precision (verified round 1).
// W pre-split into bf16 hi/lo in exact MFMA-fragment order -> B loads go
// global(L2)->registers, fully coalesced, no LDS. A (h state) distributed
// per-XCD each phase (replica in local L2), staged to LDS double-buffered.
// h packed (hi<<16|lo) u32, triple-buffered parity p%3, LLC-coherent (sc0 sc1).
// Rows sorted by length descending; inactive strips/rows skipped.
// No threadfence / no L2 writeback anywhere; one buffer_inv (L1) per phase.
// ---------------------------------------------------------------------------

namespace {
constexpr int KT0 = 40;            // L0 k-tiles of 32 (K = 1280)
constexpr int KT1 = 64;            // L1 k-tiles of 32 (K = 2048)
constexpr int NPH = 513;           // phases
constexpr int HW = 128 * 1024;     // u32 words per h parity slice
constexpr int SPIN_CAP = 3000000;
// ctr slots (int index; 64B apart)
__host__ __device__ constexpr int CREG(int x)  { return 16 + x * 16; }
__host__ __device__ constexpr int CXBAR(int x) { return 160 + x * 16; }
__host__ __device__ constexpr int CXARR(int x) { return 304 + x * 16; }
constexpr int CBOOT = 0;
constexpr int CG = 448;
}

typedef __bf16 bf16x8 __attribute__((ext_vector_type(8)));
typedef float f32x4 __attribute__((ext_vector_type(4)));
typedef unsigned short u16x4 __attribute__((ext_vector_type(4)));

__device__ __forceinline__ unsigned short f2bf(float f) {
  unsigned u = __float_as_uint(f);
  u += 0x7fffu + ((u >> 16) & 1u);
  return (unsigned short)(u >> 16);
}
__device__ __forceinline__ float bf2f(unsigned short h) {
  return __uint_as_float(((unsigned)h) << 16);
}
__device__ __forceinline__ float sigm(float x) { return 1.0f / (1.0f + __expf(-x)); }
__device__ __forceinline__ float tanh_f(float x) {
  float e = __expf(-2.0f * fabsf(x));
  float r = (1.0f - e) / (1.0f + e);
  return x >= 0.0f ? r : -r;
}

// ---- LLC-coherent (cross-XCD) accesses: bypass L1+L2 via sc0 sc1 ----------
__device__ __forceinline__ unsigned load_u32_llc(const unsigned* p) {
  unsigned v;
  asm volatile("global_load_dword %0, %1, off sc0 sc1\n\ts_waitcnt vmcnt(0)"
               : "=v"(v) : "v"(p) : "memory");
  return v;
}
__device__ __forceinline__ int load_i32_llc(const int* p) {
  int v;
  asm volatile("global_load_dword %0, %1, off sc0 sc1\n\ts_waitcnt vmcnt(0)"
               : "=v"(v) : "v"(p) : "memory");
  return v;
}
__device__ __forceinline__ uint4 load_u128_llc(const unsigned* p) {
  uint4 v;
  asm volatile("global_load_dwordx4 %0, %1, off sc0 sc1\n\ts_waitcnt vmcnt(0)"
               : "=v"(v) : "v"(p) : "memory");
  return v;
}
__device__ __forceinline__ void store_u32_llc(unsigned* p, unsigned v) {
  asm volatile("global_store_dword %0, %1, off sc0 sc1" :: "v"(p), "v"(v) : "memory");
}
__device__ __forceinline__ void release_vmem() {
  asm volatile("s_waitcnt vmcnt(0)" ::: "memory");
}
__device__ __forceinline__ void inv_l1() {
  asm volatile("buffer_inv" ::: "memory");
}
__device__ __forceinline__ int xcc_id() {
  int x;
  asm("s_getreg_b32 %0, hwreg(HW_REG_XCC_ID)" : "=s"(x));
  return x & 7;
}
__device__ __forceinline__ int spin_ge(int* p, int target) {
  for (int it = 0; it < SPIN_CAP; ++it) {
    if (load_i32_llc(p) >= target) return 1;
    __builtin_amdgcn_s_sleep(2);
  }
  return 0;
}

__device__ __forceinline__ bf16x8 frag8(const unsigned short* rowbase, int lg4) {
  u16x4 a = *(const u16x4*)(rowbase + lg4);
  u16x4 b = *(const u16x4*)(rowbase + 16 + lg4);
  return __builtin_bit_cast(bf16x8,
      __builtin_shufflevector(a, b, 0, 1, 2, 3, 4, 5, 6, 7));
}
__device__ __forceinline__ bf16x8 asbf(uint4 v) {
  return __builtin_bit_cast(bf16x8, v);
}

// ======================= prep kernels =====================================

__global__ void prep_sort(const int* __restrict__ lens, int* __restrict__ perm,
                          int* __restrict__ lenS, int* __restrict__ ncnt) {
  __shared__ int k_[128], p_[128];
  const int tid = threadIdx.x;
  if (tid < 128) { k_[tid] = (lens[tid] << 8) | (127 - tid); p_[tid] = tid; }
  __syncthreads();
  for (int ph = 0; ph < 128; ++ph) {
    if (tid < 64) {
      int a = 2 * tid + (ph & 1), b = a + 1;
      if (b < 128 && k_[a] < k_[b]) {
        int tk = k_[a]; k_[a] = k_[b]; k_[b] = tk;
        int tp = p_[a]; p_[a] = p_[b]; p_[b] = tp;
      }
    }
    __syncthreads();
  }
  if (tid < 128) { perm[tid] = p_[tid]; lenS[tid] = k_[tid] >> 8; }
  if (tid < 512) {
    int c = 0;
    for (int i = 0; i < 128; ++i) c += ((k_[i] >> 8) > tid) ? 1 : 0;
    ncnt[tid] = c;
  }
}

__global__ void prep_emb(const float* __restrict__ emb, unsigned* __restrict__ embHL) {
  int i = blockIdx.x * 256 + threadIdx.x;   // 128*256 = 32768
  float f = emb[i];
  unsigned short h = f2bf(f);
  unsigned short l = f2bf(f - bf2f(h));
  embHL[i] = ((unsigned)h << 16) | l;
}

// W[k][4096] fp32 -> fragment-direct layout:
// entry e = ((ct*KT + kt)*4 + g)*64 + l ; per entry 32B = 8 hi bf16 + 8 lo bf16
// element j: k = kt*32 + ((l>>4)&3)*4 + (j&3) + 16*(j>>2); col = g*1024 + ct*16 + (l&15)
__global__ void prep_w(const float* __restrict__ W, uint4* __restrict__ Wp, int KT) {
  int e = blockIdx.x * 256 + threadIdx.x;
  int l = e & 63;
  int g = (e >> 6) & 3;
  int ktct = e >> 8;
  int kt = ktct % KT;
  int ct = ktct / KT;
  int col = g * 1024 + ct * 16 + (l & 15);
  int kbase = kt * 32 + ((l >> 4) & 3) * 4;
  unsigned hi[8], lo[8];
#pragma unroll
  for (int j = 0; j < 8; ++j) {
    int k = kbase + (j & 3) + 16 * (j >> 2);
    float f = W[(size_t)k * 4096 + col];
    unsigned short h = f2bf(f);
    hi[j] = h;
    lo[j] = f2bf(f - bf2f(h));
  }
  uint4 vh, vl;
  vh.x = hi[0] | (hi[1] << 16); vh.y = hi[2] | (hi[3] << 16);
  vh.z = hi[4] | (hi[5] << 16); vh.w = hi[6] | (hi[7] << 16);
  vl.x = lo[0] | (lo[1] << 16); vl.y = lo[2] | (lo[3] << 16);
  vl.z = lo[4] | (lo[5] << 16); vl.w = lo[6] | (lo[7] << 16);
  Wp[(size_t)e * 2] = vh;
  Wp[(size_t)e * 2 + 1] = vl;
}

// ======================= persistent kernel =================================

__global__ __launch_bounds__(256, 1) void lstm_persist(
    const int* __restrict__ ib,
    const float* __restrict__ bias0, const float* __restrict__ bias1,
    const uint4* __restrict__ Wp0, const uint4* __restrict__ Wp1,
    const unsigned* __restrict__ embHL,
    const int* __restrict__ perm, const int* __restrict__ lenS,
    const int* __restrict__ ncnt,
    unsigned* hg0, unsigned* hg1,    // [3][128][1024] u32 packed (hi<<16|lo)
    float* cst,                      // [2][128][1024]
    unsigned* rep,                   // [8][2][128][1024]
    int* ctr, float* __restrict__ out) {
  const int bid = blockIdx.x;
  const int tid = threadIdx.x;
  const int layer = bid >> 7;
  const int sub = bid & 127;
  const int strip = sub >> 6;
  const int ct = sub & 63;
  const int r0 = strip * 64;
  const int u0 = ct * 16;
  const int KT = layer ? KT1 : KT0;
  const uint4* Wp = layer ? Wp1 : Wp0;
  const float* bias = layer ? bias1 : bias0;
  unsigned* hgL = layer ? hg1 : hg0;

  const int w = tid >> 6;
  const int rh = w >> 1, gh = w & 1;
  const int lane = tid & 63;
  const int lr = lane & 15;
  const int lg4 = ((lane >> 4) & 3) * 4;

  // staging map: 4 threads per row, 8 u32 (=8 k) per thread
  const int srow = tid >> 2;
  const int c8 = (tid & 3) * 8;
  const int sperm = perm[r0 + srow];
  // cell map: row fixed per thread
  const int crow = tid & 63;
  const int cperm = perm[r0 + crow];
  const int clen = lenS[r0 + crow];

  __shared__ __align__(16) unsigned short Ah[2][64][36];
  __shared__ __align__(16) unsigned short Al[2][64][36];
  __shared__ float zb[64][16][4];
  __shared__ int s_x, s_rk, s_R, s_NX, s_ok;

  // ---- bootstrap: XCD registration + first global sync ----
  if (tid == 0) {
    s_ok = 1;
    int x = xcc_id();
    s_x = x;
    s_rk = atomicAdd(&ctr[CREG(x)], 1);
    release_vmem();
    atomicAdd(&ctr[CBOOT], 1);
    if (!spin_ge(&ctr[CBOOT], 256)) s_ok = 0;
    int nx = 0, Rv = 1;
    for (int i = 0; i < 8; ++i) {
      int r = load_i32_llc(&ctr[CREG(i)]);
      if (r > 0) nx++;
      if (i == x) Rv = r;
    }
    s_R = Rv;
    s_NX = nx;
  }
  __syncthreads();
  const int xcd = s_x, rk = s_rk, R = s_R, NX = s_NX;
  if (!s_ok) return;
  unsigned* repH0 = rep + (size_t)xcd * 2 * HW;
  unsigned* repH1 = repH0 + HW;

  for (int p = 0; p < NPH; ++p) {
    // ---- distribute h(t-1)/h(t-2) into this XCD's replica (plain L2 data) ----
    {
      int ncopy = ncnt[p == 0 ? 0 : p - 1];
      int par0 = (p + 2) % 3;   // h0(p-1)
      int par1 = (p + 1) % 3;   // h1(p-2)
      const unsigned* src0 = hg0 + (size_t)par0 * HW;
      const unsigned* src1 = hg1 + (size_t)par1 * HW;
      const int u = tid * 4;
      for (int r = rk; r < ncopy; r += R) {
        uint4 v0 = load_u128_llc(src0 + r * 1024 + u);
        *(uint4*)&repH0[r * 1024 + u] = v0;
        uint4 v1 = load_u128_llc(src1 + r * 1024 + u);
        *(uint4*)&repH1[r * 1024 + u] = v1;
      }
    }
    release_vmem();
    __syncthreads();
    if (tid == 0) {
      atomicAdd(&ctr[CXBAR(xcd)], 1);
      if (!spin_ge(&ctr[CXBAR(xcd)], (p + 1) * R)) s_ok = 0;
    }
    __syncthreads();
    if (!s_ok) break;
    inv_l1();   // fresh L1 view of replica / c written by peers & self

    const int t = (layer == 0) ? p : p - 1;
    const bool tval = (t >= 0);
    const bool active = tval && (t < 512) && (r0 < ncnt[t]);

    if (active) {
      // ================= GEMM (full K, split-bf16 x3) =================
      f32x4 acc[2][2];
#pragma unroll
      for (int m = 0; m < 2; ++m)
#pragma unroll
        for (int gi = 0; gi < 2; ++gi)
          acc[m][gi] = (f32x4){0.f, 0.f, 0.f, 0.f};

      int tok = 0;
      if (layer == 0) tok = ib[(size_t)sperm * 512 + t];

      auto stage_regs = [&](int kt, uint4& d0, uint4& d1) {
        int kk = kt * 32 + c8;
        const unsigned* s;
        if (layer == 0)
          s = (kk < 256) ? (embHL + tok * 256 + kk)
                         : (repH0 + (r0 + srow) * 1024 + (kk - 256));
        else
          s = (kk < 1024) ? (repH0 + (r0 + srow) * 1024 + kk)
                          : (repH1 + (r0 + srow) * 1024 + (kk - 1024));
        d0 = *(const uint4*)s;
        d1 = *(const uint4*)(s + 4);
      };
      auto stage_write = [&](int buf, uint4 d0, uint4 d1) {
        unsigned dd[8] = {d0.x, d0.y, d0.z, d0.w, d1.x, d1.y, d1.z, d1.w};
        u16x4 h0_, h1_, l0_, l1_;
#pragma unroll
        for (int j = 0; j < 4; ++j) {
          h0_[j] = (unsigned short)(dd[j] >> 16);
          l0_[j] = (unsigned short)(dd[j] & 0xffffu);
          h1_[j] = (unsigned short)(dd[4 + j] >> 16);
          l1_[j] = (unsigned short)(dd[4 + j] & 0xffffu);
        }
        *(u16x4*)&Ah[buf][srow][c8] = h0_;
        *(u16x4*)&Ah[buf][srow][c8 + 4] = h1_;
        *(u16x4*)&Al[buf][srow][c8] = l0_;
        *(u16x4*)&Al[buf][srow][c8 + 4] = l1_;
      };

      uint4 sd0, sd1;
      stage_regs(0, sd0, sd1);
      stage_write(0, sd0, sd1);
      __syncthreads();

      for (int kt = 0; kt < KT; ++kt) {
        const int buf = kt & 1;
        if (kt + 1 < KT) stage_regs(kt + 1, sd0, sd1);
        // B frags direct from global (fragment-order Wp, L2-resident)
        const uint4* wb = Wp + ((size_t)((ct * KT + kt) * 4 + gh * 2) * 64 + lane) * 2;
        bf16x8 bh0 = asbf(wb[0]),   bl0 = asbf(wb[1]);
        bf16x8 bh1 = asbf(wb[128]), bl1 = asbf(wb[129]);
        // A frags from LDS
        bf16x8 ah[2], al[2];
#pragma unroll
        for (int m = 0; m < 2; ++m) {
          int arow = rh * 32 + m * 16 + lr;
          ah[m] = frag8(&Ah[buf][arow][0], lg4);
          al[m] = frag8(&Al[buf][arow][0], lg4);
        }
#pragma unroll
        for (int m = 0; m < 2; ++m) {
          acc[m][0] = __builtin_amdgcn_mfma_f32_16x16x32_bf16(ah[m], bh0, acc[m][0], 0, 0, 0);
          acc[m][0] = __builtin_amdgcn_mfma_f32_16x16x32_bf16(ah[m], bl0, acc[m][0], 0, 0, 0);
          acc[m][0] = __builtin_amdgcn_mfma_f32_16x16x32_bf16(al[m], bh0, acc[m][0], 0, 0, 0);
          acc[m][1] = __builtin_amdgcn_mfma_f32_16x16x32_bf16(ah[m], bh1, acc[m][1], 0, 0, 0);
          acc[m][1] = __builtin_amdgcn_mfma_f32_16x16x32_bf16(ah[m], bl1, acc[m][1], 0, 0, 0);
          acc[m][1] = __builtin_amdgcn_mfma_f32_16x16x32_bf16(al[m], bh1, acc[m][1], 0, 0, 0);
        }
        if (kt + 1 < KT) stage_write((kt + 1) & 1, sd0, sd1);
        __syncthreads();
      }

      // ================= z exchange + fused cell =================
#pragma unroll
      for (int m = 0; m < 2; ++m)
#pragma unroll
        for (int gi = 0; gi < 2; ++gi)
#pragma unroll
          for (int rr = 0; rr < 4; ++rr)
            zb[rh * 32 + m * 16 + lg4 + rr][lr][gh * 2 + gi] = acc[m][gi][rr];
      __syncthreads();

      if (t < clen) {   // active row
        const int pw = layer ? (p + 2) % 3 : p % 3;
        const int rg = r0 + crow;
#pragma unroll
        for (int i = 0; i < 4; ++i) {
          int uu = i * 4 + (tid >> 6);
          int ug = u0 + uu;
          float zi = zb[crow][uu][0] + bias[ug];
          float zj = zb[crow][uu][1] + bias[1024 + ug];
          float zf = zb[crow][uu][2] + bias[2048 + ug];
          float zo = zb[crow][uu][3] + bias[3072 + ug];
          float* cp = &cst[(size_t)(layer * 128 + rg) * 1024 + ug];
          float nc = (*cp) * sigm(zf + 1.0f) + sigm(zi) * tanh_f(zj);
          float nh = tanh_f(nc) * sigm(zo);
          *cp = nc;
          unsigned short hh = f2bf(nh);
          unsigned hp = ((unsigned)hh << 16) | f2bf(nh - bf2f(hh));
          unsigned idx = (unsigned)rg * 1024 + ug;
          store_u32_llc(&hgL[(size_t)pw * HW + idx], hp);
          if (t == clen - 1)   // freeze: extra parity (3rd covered next phase)
            store_u32_llc(&hgL[(size_t)((pw + 1) % 3) * HW + idx], hp);
          if (layer) out[(size_t)cperm * 1024 + ug] = nh;
        }
      }
    }

    // deferred freeze fixup: rows that froze LAST phase get their 3rd parity
    if (tval && t == clen) {
      const int pw = layer ? (p + 2) % 3 : p % 3;
      const int rg = r0 + crow;
#pragma unroll
      for (int i = 0; i < 4; ++i) {
        int uu = i * 4 + (tid >> 6);
        unsigned idx = (unsigned)rg * 1024 + u0 + uu;
        unsigned v = load_u32_llc(&hgL[(size_t)pw * HW + idx]);
        store_u32_llc(&hgL[(size_t)((pw + 1) % 3) * HW + idx], v);
      }
    }

    // ---- 2-level grid barrier (release: vmcnt only; no cache flush) ----
    release_vmem();
    __syncthreads();
    if (tid == 0) {
      int o = atomicAdd(&ctr[CXARR(xcd)], 1);
      if (o == (p + 1) * R - 1) atomicAdd(&ctr[CG], 1);
      if (!spin_ge(&ctr[CG], (p + 1) * NX)) s_ok = 0;
    }
    __syncthreads();
    if (!s_ok) break;
  }
}

// ======================= host launch =======================================

extern "C" void kernel_launch(void* const* d_in, const int* in_sizes, int n_in,
                              void* d_out, int out_size, void* d_ws, size_t ws_size,
                              hipStream_t stream) {
  const int*   ib   = (const int*)d_in[0];
  const int*   lens = (const int*)d_in[1];
  const float* emb  = (const float*)d_in[2];
  const float* W0   = (const float*)d_in[3];
  const float* b0   = (const float*)d_in[4];
  const float* W1   = (const float*)d_in[5];
  const float* b1   = (const float*)d_in[6];
  (void)in_sizes; (void)n_in; (void)out_size; (void)ws_size;

  char* ws = (char*)d_ws;
  size_t off = 0;
  auto alloc = [&](size_t bytes) { char* q = ws + off; off += (bytes + 255) & ~(size_t)255; return q; };

  int*      ctr   = (int*)alloc(4096);
  unsigned* hg0   = (unsigned*)alloc((size_t)3 * HW * 4);
  unsigned* hg1   = (unsigned*)alloc((size_t)3 * HW * 4);
  float*    cst   = (float*)alloc((size_t)2 * HW * 4);
  const size_t zero_bytes = off;
  unsigned* embHL = (unsigned*)alloc(128 * 256 * 4);
  int*      perm  = (int*)alloc(4096);          // perm[128], lenS[128], ncnt[512]
  int*      lenS  = perm + 128;
  int*      ncnt  = perm + 256;
  unsigned* rep   = (unsigned*)alloc((size_t)8 * 2 * HW * 4);
  uint4*    Wp0   = (uint4*)alloc((size_t)64 * KT0 * 4 * 64 * 32);
  uint4*    Wp1   = (uint4*)alloc((size_t)64 * KT1 * 4 * 64 * 32);

  hipMemsetAsync(d_ws, 0, zero_bytes, stream);
  prep_sort<<<1, 512, 0, stream>>>(lens, perm, lenS, ncnt);
  prep_emb<<<128, 256, 0, stream>>>(emb, embHL);
  prep_w<<<(64 * KT0 * 4 * 64) / 256, 256, 0, stream>>>(W0, Wp0, KT0);
  prep_w<<<(64 * KT1 * 4 * 64) / 256, 256, 0, stream>>>(W1, Wp1, KT1);
  lstm_persist<<<256, 256, 0, stream>>>(ib, b0, b1, Wp0, Wp1, embHL,
                                        perm, lenS, ncnt, hg0, hg1, cst,
                                        rep, ctr, (float*)d_out);
}

// Round 3
// 27142.331 us; speedup vs baseline: 4.3549x; 1.0075x over previous
//
#include <hip/hip_runtime.h>

// ---------------------------------------------------------------------------
// 2-layer LSTM encoder, B=128 T=512 E=256 H=1024 (round 3).
// Persistent kernel: 256 blocks x 512 threads (8 waves), 1 grid-sync/phase.
// Every block owns 4 L0-units AND 4 L1-units (16 cols each layer);
// per phase p: L0 GEMM+cell at t=p, L1 GEMM+cell at t=p-1 (fused kt loop,
// h0 tiles staged once feed both layers). Split-bf16 x3 MFMA (verified r1/r2).
// W-hi: LDS-resident per block (104 KB, loaded once). W-lo: L2-resident
// (3.25 MB/XCD), streamed to regs with 1-kt prefetch. A (h) via per-XCD
// replica in local L2, staged to LDS double-buffered, 16-row work gating
// from sorted lengths (active rows = exact prefix -> no stale reads).
// ---------------------------------------------------------------------------

namespace {
constexpr int NBLK = 256, THREADS = 512;
constexpr int KT0B = 40;           // L0 B k-tiles (K=1280: 8 x-tiles + 32 h0)
constexpr int KT1B = 64;           // L1 B k-tiles (K=2048: 32 h0 + 32 h1)
constexpr int KT_ALL = 72;         // fused: 8 X + 32 h0 + 32 h1
constexpr int NPH = 513;
constexpr int HW = 128 * 1024;     // u32 words per h parity slice
constexpr int SPIN_CAP = 3000000;
__host__ __device__ constexpr int CREG(int x)  { return 16 + x * 16; }
__host__ __device__ constexpr int CXBAR(int x) { return 160 + x * 16; }
__host__ __device__ constexpr int CXARR(int x) { return 304 + x * 16; }
constexpr int CBOOT = 0;
constexpr int CG = 448;
}

typedef __bf16 bf16x8 __attribute__((ext_vector_type(8)));
typedef float f32x4 __attribute__((ext_vector_type(4)));
typedef unsigned short u16x4 __attribute__((ext_vector_type(4)));

__device__ __forceinline__ unsigned short f2bf(float f) {
  unsigned u = __float_as_uint(f);
  u += 0x7fffu + ((u >> 16) & 1u);
  return (unsigned short)(u >> 16);
}
__device__ __forceinline__ float bf2f(unsigned short h) {
  return __uint_as_float(((unsigned)h) << 16);
}
__device__ __forceinline__ float sigm(float x) { return 1.0f / (1.0f + __expf(-x)); }
__device__ __forceinline__ float tanh_f(float x) {
  float e = __expf(-2.0f * fabsf(x));
  float r = (1.0f - e) / (1.0f + e);
  return x >= 0.0f ? r : -r;
}

__device__ __forceinline__ int load_i32_llc(const int* p) {
  int v;
  asm volatile("global_load_dword %0, %1, off sc0 sc1\n\ts_waitcnt vmcnt(0)"
               : "=v"(v) : "v"(p) : "memory");
  return v;
}
__device__ __forceinline__ uint4 load_u128_llc(const unsigned* p) {
  uint4 v;
  asm volatile("global_load_dwordx4 %0, %1, off sc0 sc1\n\ts_waitcnt vmcnt(0)"
               : "=v"(v) : "v"(p) : "memory");
  return v;
}
__device__ __forceinline__ void store_u32_llc(unsigned* p, unsigned v) {
  asm volatile("global_store_dword %0, %1, off sc0 sc1" :: "v"(p), "v"(v) : "memory");
}
__device__ __forceinline__ void release_vmem() {
  asm volatile("s_waitcnt vmcnt(0)" ::: "memory");
}
__device__ __forceinline__ void inv_l1() {
  asm volatile("buffer_inv" ::: "memory");
}
__device__ __forceinline__ int xcc_id() {
  int x;
  asm("s_getreg_b32 %0, hwreg(HW_REG_XCC_ID)" : "=s"(x));
  return x & 7;
}
__device__ __forceinline__ int spin_ge(int* p, int target) {
  for (int it = 0; it < SPIN_CAP; ++it) {
    if (load_i32_llc(p) >= target) return 1;
    __builtin_amdgcn_s_sleep(2);
  }
  return 0;
}

__device__ __forceinline__ bf16x8 frag8(const unsigned short* rowbase, int lg4) {
  u16x4 a = *(const u16x4*)(rowbase + lg4);
  u16x4 b = *(const u16x4*)(rowbase + 16 + lg4);
  return __builtin_bit_cast(bf16x8,
      __builtin_shufflevector(a, b, 0, 1, 2, 3, 4, 5, 6, 7));
}
__device__ __forceinline__ bf16x8 asbf(uint4 v) {
  return __builtin_bit_cast(bf16x8, v);
}

// ======================= prep kernels =====================================

__global__ void prep_sort(const int* __restrict__ lens, int* __restrict__ perm,
                          int* __restrict__ lenS, int* __restrict__ ncnt) {
  __shared__ int k_[128], p_[128];
  const int tid = threadIdx.x;
  if (tid < 128) { k_[tid] = (lens[tid] << 8) | (127 - tid); p_[tid] = tid; }
  __syncthreads();
  for (int ph = 0; ph < 128; ++ph) {
    if (tid < 64) {
      int a = 2 * tid + (ph & 1), b = a + 1;
      if (b < 128 && k_[a] < k_[b]) {
        int tk = k_[a]; k_[a] = k_[b]; k_[b] = tk;
        int tp = p_[a]; p_[a] = p_[b]; p_[b] = tp;
      }
    }
    __syncthreads();
  }
  if (tid < 128) { perm[tid] = p_[tid]; lenS[tid] = k_[tid] >> 8; }
  if (tid < 512) {
    int c = 0;
    for (int i = 0; i < 128; ++i) c += ((k_[i] >> 8) > tid) ? 1 : 0;
    ncnt[tid] = c;
  }
}

__global__ void prep_emb(const float* __restrict__ emb, unsigned* __restrict__ embHL) {
  int i = blockIdx.x * 256 + threadIdx.x;   // 128*256 = 32768
  float f = emb[i];
  unsigned short h = f2bf(f);
  unsigned short l = f2bf(f - bf2f(h));
  embHL[i] = ((unsigned)h << 16) | l;
}

// W[k][4096] -> per-block frag slabs: e = (blk*KT + kt)*64 + lane.
// lane: cf = lane&15 = u_local*4 + g ; col = g*1024 + blk*4 + u_local
// elem j: k = kt*32 + ((lane>>4)&3)*4 + (j&3) + 16*(j>>2)
__global__ void prep_wslab(const float* __restrict__ W, uint4* __restrict__ Whi,
                           uint4* __restrict__ Wlo, int KT) {
  int e = blockIdx.x * 256 + threadIdx.x;
  int lane = e & 63;
  int kt = (e >> 6) % KT;
  int blk = e / (64 * KT);
  int cf = lane & 15;
  int g = cf & 3, ul = cf >> 2;
  int col = g * 1024 + blk * 4 + ul;
  int kbase = kt * 32 + ((lane >> 4) & 3) * 4;
  unsigned hi[8], lo[8];
#pragma unroll
  for (int j = 0; j < 8; ++j) {
    int k = kbase + (j & 3) + 16 * (j >> 2);
    float f = W[(size_t)k * 4096 + col];
    unsigned short h = f2bf(f);
    hi[j] = h;
    lo[j] = f2bf(f - bf2f(h));
  }
  uint4 vh, vl;
  vh.x = hi[0] | (hi[1] << 16); vh.y = hi[2] | (hi[3] << 16);
  vh.z = hi[4] | (hi[5] << 16); vh.w = hi[6] | (hi[7] << 16);
  vl.x = lo[0] | (lo[1] << 16); vl.y = lo[2] | (lo[3] << 16);
  vl.z = lo[4] | (lo[5] << 16); vl.w = lo[6] | (lo[7] << 16);
  Whi[e] = vh;
  Wlo[e] = vl;
}

// ======================= persistent kernel =================================

__global__ __launch_bounds__(THREADS, 1) void lstm_persist(
    const int* __restrict__ ib,
    const float* __restrict__ bias0, const float* __restrict__ bias1,
    const uint4* __restrict__ Whi0g, const uint4* __restrict__ Wlo0g,
    const uint4* __restrict__ Whi1g, const uint4* __restrict__ Wlo1g,
    const unsigned* __restrict__ embHL,
    const int* __restrict__ perm, const int* __restrict__ lenS,
    const int* __restrict__ ncnt,
    unsigned* hg0, unsigned* hg1,    // [3][128][1024] u32 packed (hi<<16|lo)
    float* cst,                      // [2][128][1024]
    unsigned* rep,                   // [8][2][128][1024]
    int* ctr, float* __restrict__ out) {
  const int blk = blockIdx.x;
  const int tid = threadIdx.x;
  const int w = tid >> 6;                 // wave 0..7 -> rows w*16..w*16+15
  const int lane = tid & 63;
  const int lr = lane & 15;
  const int lg4 = ((lane >> 4) & 3) * 4;
  const int srow = tid >> 2;              // staging/cell row 0..127
  const int c8 = (tid & 3) * 8;           // staging u32 offset within 32
  const int cu = tid & 3;                 // cell unit 0..3
  const int ug = blk * 4 + cu;            // global unit
  const int cperm = perm[srow];
  const int clen = lenS[srow];

  __shared__ uint4 Wh0[KT0B * 64];                       // 40 KB
  __shared__ uint4 Wh1[KT1B * 64];                       // 64 KB
  __shared__ __align__(16) unsigned short Ah[2][128][36];// 18 KB x? (36 KB both)
  __shared__ __align__(16) unsigned short Al[2][128][36];
  __shared__ float zb[2][128][17];                       // 17 KB
  __shared__ int s_x, s_rk, s_R, s_NX, s_ok;

  // ---- one-time: W-hi slabs -> LDS ----
  {
    const uint4* s0 = Whi0g + (size_t)blk * (KT0B * 64);
    for (int i = tid; i < KT0B * 64; i += THREADS) Wh0[i] = s0[i];
    const uint4* s1 = Whi1g + (size_t)blk * (KT1B * 64);
    for (int i = tid; i < KT1B * 64; i += THREADS) Wh1[i] = s1[i];
  }

  // hoist biases / c pointers
  float bz0[4], bz1[4];
#pragma unroll
  for (int g = 0; g < 4; ++g) {
    bz0[g] = bias0[g * 1024 + ug];
    bz1[g] = bias1[g * 1024 + ug];
  }
  float* c0p = &cst[(size_t)srow * 1024 + ug];
  float* c1p = &cst[(size_t)(128 + srow) * 1024 + ug];

  // ---- bootstrap: XCD registration + first global sync ----
  if (tid == 0) {
    s_ok = 1;
    int x = xcc_id();
    s_x = x;
    s_rk = atomicAdd(&ctr[CREG(x)], 1);
    release_vmem();
    atomicAdd(&ctr[CBOOT], 1);
    if (!spin_ge(&ctr[CBOOT], NBLK)) s_ok = 0;
    int nx = 0, Rv = 1;
    for (int i = 0; i < 8; ++i) {
      int r = load_i32_llc(&ctr[CREG(i)]);
      if (r > 0) nx++;
      if (i == x) Rv = r;
    }
    s_R = Rv;
    s_NX = nx;
  }
  __syncthreads();
  const int xcd = s_x, rk = s_rk, R = s_R, NX = s_NX;
  if (!s_ok) return;
  unsigned* repH0 = rep + (size_t)xcd * 2 * HW;
  unsigned* repH1 = repH0 + HW;

  const uint4* wl0g = Wlo0g + (size_t)blk * (KT0B * 64) + lane;
  const uint4* wl1g = Wlo1g + (size_t)blk * (KT1B * 64) + lane;

  for (int p = 0; p < NPH; ++p) {
    // ---- distribute h0(p-1), h1(p-2) into this XCD's replica ----
    {
      int ncopy = ncnt[p == 0 ? 0 : p - 1];
      const unsigned* src0 = hg0 + (size_t)((p + 2) % 3) * HW;
      const unsigned* src1 = hg1 + (size_t)((p + 1) % 3) * HW;
      if (tid < 256) {
        const int u = tid * 4;
        for (int r = rk; r < ncopy; r += R) {
          uint4 v0 = load_u128_llc(src0 + r * 1024 + u);
          *(uint4*)&repH0[r * 1024 + u] = v0;
          uint4 v1 = load_u128_llc(src1 + r * 1024 + u);
          *(uint4*)&repH1[r * 1024 + u] = v1;
        }
      }
    }
    release_vmem();
    __syncthreads();
    if (tid == 0) {
      atomicAdd(&ctr[CXBAR(xcd)], 1);
      if (!spin_ge(&ctr[CXBAR(xcd)], (p + 1) * R)) s_ok = 0;
    }
    __syncthreads();
    if (!s_ok) break;
    inv_l1();

    const int nact0 = (p < 512) ? ncnt[p] : 0;          // L0 active rows (t=p)
    const int nact1 = (p >= 1) ? ncnt[p - 1] : 0;       // L1 active rows (t=p-1)
    const int na = nact0 > nact1 ? nact0 : nact1;
    const int limit = (na + 15) & ~15;                  // staged rows

    if (limit > 0) {
      // ================= fused dual-layer GEMM =================
      f32x4 acc0 = (f32x4){0.f, 0.f, 0.f, 0.f};
      f32x4 acc1 = (f32x4){0.f, 0.f, 0.f, 0.f};

      int tok = 0;
      if (p < 512 && srow < limit) tok = ib[(size_t)cperm * 512 + p];

      auto stage_regs = [&](int kt, uint4& d0, uint4& d1) {
        if (srow >= limit) return;
        const int kk = kt * 32 + c8;
        const unsigned* s;
        if (kt < 8)       s = embHL + tok * 256 + kk;
        else if (kt < 40) s = repH0 + srow * 1024 + (kk - 256);
        else              s = repH1 + srow * 1024 + (kk - 1280);
        d0 = *(const uint4*)s;
        d1 = *(const uint4*)(s + 4);
      };
      auto stage_write = [&](int buf, uint4 d0, uint4 d1) {
        if (srow >= limit) return;
        unsigned dd[8] = {d0.x, d0.y, d0.z, d0.w, d1.x, d1.y, d1.z, d1.w};
        u16x4 h0_, h1_, l0_, l1_;
#pragma unroll
        for (int j = 0; j < 4; ++j) {
          h0_[j] = (unsigned short)(dd[j] >> 16);
          l0_[j] = (unsigned short)(dd[j] & 0xffffu);
          h1_[j] = (unsigned short)(dd[4 + j] >> 16);
          l1_[j] = (unsigned short)(dd[4 + j] & 0xffffu);
        }
        *(u16x4*)&Ah[buf][srow][c8] = h0_;
        *(u16x4*)&Ah[buf][srow][c8 + 4] = h1_;
        *(u16x4*)&Al[buf][srow][c8] = l0_;
        *(u16x4*)&Al[buf][srow][c8 + 4] = l1_;
      };

      const int ktEnd = (nact1 > 0) ? KT_ALL : KT0B;
      uint4 sd0, sd1;
      stage_regs(0, sd0, sd1);
      stage_write(0, sd0, sd1);
      __syncthreads();

      uint4 nl0 = wl0g[0];      // W-lo L0 frag, kt=0
      uint4 nl1 = wl1g[0];      // W-lo L1 frag, kt=8

      for (int kt = 0; kt < ktEnd; ++kt) {
        const int buf = kt & 1;
        const uint4 cl0 = nl0, cl1 = nl1;
        if (kt + 1 < ktEnd) stage_regs(kt + 1, sd0, sd1);
        if (kt + 1 < KT0B) nl0 = wl0g[(size_t)(kt + 1) * 64];
        if (kt + 1 >= 8 && kt + 1 < KT_ALL) nl1 = wl1g[(size_t)(kt - 7) * 64];

        const bool do0 = (kt < KT0B) && (w * 16 < nact0);
        const bool do1 = (kt >= 8) && (w * 16 < nact1);
        if (do0 || do1) {
          const bf16x8 ah = frag8(&Ah[buf][w * 16 + lr][0], lg4);
          const bf16x8 al = frag8(&Al[buf][w * 16 + lr][0], lg4);
          if (do0) {
            const bf16x8 bh = asbf(Wh0[kt * 64 + lane]);
            const bf16x8 bl = asbf(cl0);
            acc0 = __builtin_amdgcn_mfma_f32_16x16x32_bf16(ah, bh, acc0, 0, 0, 0);
            acc0 = __builtin_amdgcn_mfma_f32_16x16x32_bf16(ah, bl, acc0, 0, 0, 0);
            acc0 = __builtin_amdgcn_mfma_f32_16x16x32_bf16(al, bh, acc0, 0, 0, 0);
          }
          if (do1) {
            const bf16x8 bh = asbf(Wh1[(kt - 8) * 64 + lane]);
            const bf16x8 bl = asbf(cl1);
            acc1 = __builtin_amdgcn_mfma_f32_16x16x32_bf16(ah, bh, acc1, 0, 0, 0);
            acc1 = __builtin_amdgcn_mfma_f32_16x16x32_bf16(ah, bl, acc1, 0, 0, 0);
            acc1 = __builtin_amdgcn_mfma_f32_16x16x32_bf16(al, bh, acc1, 0, 0, 0);
          }
        }
        if (kt + 1 < ktEnd) stage_write((kt + 1) & 1, sd0, sd1);
        __syncthreads();
      }

      // ================= z exchange =================
      if (w * 16 < nact0) {
#pragma unroll
        for (int rr = 0; rr < 4; ++rr)
          zb[0][w * 16 + lg4 + rr][lr] = acc0[rr];
      }
      if (w * 16 < nact1) {
#pragma unroll
        for (int rr = 0; rr < 4; ++rr)
          zb[1][w * 16 + lg4 + rr][lr] = acc1[rr];
      }
      __syncthreads();

      // ================= fused cells (thread = row x unit) =================
      if (p < clen) {               // L0, t = p
        const float zi = zb[0][srow][cu * 4 + 0] + bz0[0];
        const float zj = zb[0][srow][cu * 4 + 1] + bz0[1];
        const float zf = zb[0][srow][cu * 4 + 2] + bz0[2];
        const float zo = zb[0][srow][cu * 4 + 3] + bz0[3];
        const float nc = (*c0p) * sigm(zf + 1.0f) + sigm(zi) * tanh_f(zj);
        const float nh = tanh_f(nc) * sigm(zo);
        *c0p = nc;
        unsigned short hh = f2bf(nh);
        unsigned hp = ((unsigned)hh << 16) | f2bf(nh - bf2f(hh));
        store_u32_llc(&hg0[(size_t)(p % 3) * HW + srow * 1024 + ug], hp);
      }
      if (p >= 1 && (p - 1) < clen) {   // L1, t = p-1
        const float zi = zb[1][srow][cu * 4 + 0] + bz1[0];
        const float zj = zb[1][srow][cu * 4 + 1] + bz1[1];
        const float zf = zb[1][srow][cu * 4 + 2] + bz1[2];
        const float zo = zb[1][srow][cu * 4 + 3] + bz1[3];
        const float nc = (*c1p) * sigm(zf + 1.0f) + sigm(zi) * tanh_f(zj);
        const float nh = tanh_f(nc) * sigm(zo);
        *c1p = nc;
        unsigned short hh = f2bf(nh);
        unsigned hp = ((unsigned)hh << 16) | f2bf(nh - bf2f(hh));
        store_u32_llc(&hg1[(size_t)((p + 2) % 3) * HW + srow * 1024 + ug], hp);
        out[(size_t)cperm * 1024 + ug] = nh;   // overwritten until last step
      }
    }

    // ---- 2-level grid barrier ----
    release_vmem();
    __syncthreads();
    if (tid == 0) {
      int o = atomicAdd(&ctr[CXARR(xcd)], 1);
      if (o == (p + 1) * R - 1) atomicAdd(&ctr[CG], 1);
      if (!spin_ge(&ctr[CG], (p + 1) * NX)) s_ok = 0;
    }
    __syncthreads();
    if (!s_ok) break;
  }
}

// ======================= host launch =======================================

extern "C" void kernel_launch(void* const* d_in, const int* in_sizes, int n_in,
                              void* d_out, int out_size, void* d_ws, size_t ws_size,
                              hipStream_t stream) {
  const int*   ib   = (const int*)d_in[0];
  const int*   lens = (const int*)d_in[1];
  const float* emb  = (const float*)d_in[2];
  const float* W0   = (const float*)d_in[3];
  const float* b0   = (const float*)d_in[4];
  const float* W1   = (const float*)d_in[5];
  const float* b1   = (const float*)d_in[6];
  (void)in_sizes; (void)n_in; (void)out_size; (void)ws_size;

  char* ws = (char*)d_ws;
  size_t off = 0;
  auto alloc = [&](size_t bytes) { char* q = ws + off; off += (bytes + 255) & ~(size_t)255; return q; };

  int*      ctr   = (int*)alloc(4096);
  unsigned* hg0   = (unsigned*)alloc((size_t)3 * HW * 4);
  unsigned* hg1   = (unsigned*)alloc((size_t)3 * HW * 4);
  float*    cst   = (float*)alloc((size_t)2 * HW * 4);
  const size_t zero_bytes = off;
  unsigned* embHL = (unsigned*)alloc(128 * 256 * 4);
  int*      perm  = (int*)alloc(4096);          // perm[128], lenS[128], ncnt[512]
  int*      lenS  = perm + 128;
  int*      ncnt  = perm + 256;
  unsigned* rep   = (unsigned*)alloc((size_t)8 * 2 * HW * 4);
  uint4*    Whi0  = (uint4*)alloc((size_t)NBLK * KT0B * 64 * 16);
  uint4*    Wlo0  = (uint4*)alloc((size_t)NBLK * KT0B * 64 * 16);
  uint4*    Whi1  = (uint4*)alloc((size_t)NBLK * KT1B * 64 * 16);
  uint4*    Wlo1  = (uint4*)alloc((size_t)NBLK * KT1B * 64 * 16);

  hipMemsetAsync(d_ws, 0, zero_bytes, stream);
  prep_sort<<<1, 512, 0, stream>>>(lens, perm, lenS, ncnt);
  prep_emb<<<128, 256, 0, stream>>>(emb, embHL);
  prep_wslab<<<(NBLK * KT0B * 64) / 256, 256, 0, stream>>>(W0, Whi0, Wlo0, KT0B);
  prep_wslab<<<(NBLK * KT1B * 64) / 256, 256, 0, stream>>>(W1, Whi1, Wlo1, KT1B);
  lstm_persist<<<NBLK, THREADS, 0, stream>>>(ib, b0, b1, Whi0, Wlo0, Whi1, Wlo1,
                                             embHL, perm, lenS, ncnt, hg0, hg1,
                                             cst, rep, ctr, (float*)d_out);
}

// Round 4
// 23298.541 us; speedup vs baseline: 5.0734x; 1.1650x over previous
//
#include <hip/hip_runtime.h>

// ---------------------------------------------------------------------------
// 2-layer LSTM encoder, B=128 T=512 E=256 H=1024 (round 4).
// Persistent kernel: 256 blocks x 512 threads. Per phase p:
//   L0 (t=p):   z0 = [x_p ; h0(p-1)] @ W0 -> cell -> h0(p)
//   L1 (t=p-1): z1 = [h0(p-1) ; h1(p-2)] @ W1 -> cell -> h1(p-1)
// Split-bf16 x3 MFMA (verified r1-r3). W-hi LDS-resident; W-lo streamed.
// NEW this round:
//  - h as separate hi/lo bf16 planes; A-frags loaded DIRECTLY global->reg
//    from per-XCD replica (one 64B line per row per kt). No A LDS staging,
//    NO barriers in the kt loops.
//  - Flag-based barriers (plain sc0sc1 stores + parallel polling), no atomics.
//  - Batched distribution loads (issue 4, single vmcnt wait).
//  - c-state in registers.
// ---------------------------------------------------------------------------

namespace {
constexpr int NBLK = 256, THREADS = 512;
constexpr int KT0B = 40;           // L0 k-tiles of 32 (K=1280)
constexpr int KT1B = 64;           // L1 k-tiles of 32 (K=2048)
constexpr int NPH = 513;
constexpr int HP = 128 * 1024;     // u16 elems per h plane
constexpr int SPIN_CAP = 2000000;
// flag slots (u32 index into ctr[1024])
constexpr int F_CREG = 0;          // 8 x 16 (boot atomics)
constexpr int F_BOOT = 128;
constexpr int F_ARR  = 256;        // 256 contiguous
constexpr int F_GO   = 520;
constexpr int F_XARR = 576;        // 8 x 32
constexpr int F_XGO  = 832;        // 8 x 16
}

typedef __bf16 bf16x8 __attribute__((ext_vector_type(8)));
typedef float f32x4 __attribute__((ext_vector_type(4)));
typedef unsigned short u16x4 __attribute__((ext_vector_type(4)));

__device__ __forceinline__ unsigned short f2bf(float f) {
  unsigned u = __float_as_uint(f);
  u += 0x7fffu + ((u >> 16) & 1u);
  return (unsigned short)(u >> 16);
}
__device__ __forceinline__ float bf2f(unsigned short h) {
  return __uint_as_float(((unsigned)h) << 16);
}
__device__ __forceinline__ float sigm(float x) { return 1.0f / (1.0f + __expf(-x)); }
__device__ __forceinline__ float tanh_f(float x) {
  float e = __expf(-2.0f * fabsf(x));
  float r = (1.0f - e) / (1.0f + e);
  return x >= 0.0f ? r : -r;
}

// ---- LLC-coherent ops (bypass L1+L2) --------------------------------------
__device__ __forceinline__ int load_i32_llc(const int* p) {
  int v;
  asm volatile("global_load_dword %0, %1, off sc0 sc1\n\ts_waitcnt vmcnt(0)"
               : "=v"(v) : "v"(p) : "memory");
  return v;
}
__device__ __forceinline__ uint4 llc_load_issue(const unsigned* p) {
  uint4 v;
  asm volatile("global_load_dwordx4 %0, %1, off sc0 sc1" : "=v"(v) : "v"(p));
  return v;
}
__device__ __forceinline__ void vm_wait0() {
  asm volatile("s_waitcnt vmcnt(0)" ::: "memory");
  __builtin_amdgcn_sched_barrier(0);
}
__device__ __forceinline__ void store_u32_llc(unsigned* p, unsigned v) {
  asm volatile("global_store_dword %0, %1, off sc0 sc1" :: "v"(p), "v"(v) : "memory");
}
__device__ __forceinline__ void store_u16_llc(unsigned short* p, unsigned short v) {
  asm volatile("global_store_short %0, %1, off sc0 sc1" :: "v"(p), "v"(v) : "memory");
}
__device__ __forceinline__ void inv_l1() {
  asm volatile("buffer_inv" ::: "memory");
}
__device__ __forceinline__ int xcc_id() {
  int x;
  asm("s_getreg_b32 %0, hwreg(HW_REG_XCC_ID)" : "=s"(x));
  return x & 7;
}
__device__ __forceinline__ int spin_ge(int* p, int target) {
  for (int it = 0; it < SPIN_CAP; ++it) {
    if (load_i32_llc(p) >= target) return 1;
    __builtin_amdgcn_s_sleep(1);
  }
  return 0;
}

__device__ __forceinline__ bf16x8 frag2(const unsigned short* pk) {
  u16x4 a = *(const u16x4*)pk;
  u16x4 b = *(const u16x4*)(pk + 16);
  return __builtin_bit_cast(bf16x8,
      __builtin_shufflevector(a, b, 0, 1, 2, 3, 4, 5, 6, 7));
}
__device__ __forceinline__ bf16x8 asbf(uint4 v) {
  return __builtin_bit_cast(bf16x8, v);
}

#define MFMA3(acc, ah, al, bh, bl)                                            \
  acc = __builtin_amdgcn_mfma_f32_16x16x32_bf16(ah, bh, acc, 0, 0, 0);        \
  acc = __builtin_amdgcn_mfma_f32_16x16x32_bf16(ah, bl, acc, 0, 0, 0);        \
  acc = __builtin_amdgcn_mfma_f32_16x16x32_bf16(al, bh, acc, 0, 0, 0);

// ======================= prep kernels =====================================

__global__ void prep_sort(const int* __restrict__ lens, int* __restrict__ perm,
                          int* __restrict__ lenS, int* __restrict__ ncnt) {
  __shared__ int k_[128], p_[128];
  const int tid = threadIdx.x;
  if (tid < 128) { k_[tid] = (lens[tid] << 8) | (127 - tid); p_[tid] = tid; }
  __syncthreads();
  for (int ph = 0; ph < 128; ++ph) {
    if (tid < 64) {
      int a = 2 * tid + (ph & 1), b = a + 1;
      if (b < 128 && k_[a] < k_[b]) {
        int tk = k_[a]; k_[a] = k_[b]; k_[b] = tk;
        int tp = p_[a]; p_[a] = p_[b]; p_[b] = tp;
      }
    }
    __syncthreads();
  }
  if (tid < 128) { perm[tid] = p_[tid]; lenS[tid] = k_[tid] >> 8; }
  if (tid < 512) {
    int c = 0;
    for (int i = 0; i < 128; ++i) c += ((k_[i] >> 8) > tid) ? 1 : 0;
    ncnt[tid] = c;
  }
}

__global__ void prep_emb(const float* __restrict__ emb,
                         unsigned short* __restrict__ ehi,
                         unsigned short* __restrict__ elo) {
  int i = blockIdx.x * 256 + threadIdx.x;   // 32768
  float f = emb[i];
  unsigned short h = f2bf(f);
  ehi[i] = h;
  elo[i] = f2bf(f - bf2f(h));
}

// W[k][4096] -> per-block frag slabs: e = (blk*KT + kt)*64 + lane.
// lane: cf = lane&15 = u_local*4 + g ; col = g*1024 + blk*4 + u_local
// elem j: k = kt*32 + ((lane>>4)&3)*4 + (j&3) + 16*(j>>2)
__global__ void prep_wslab(const float* __restrict__ W, uint4* __restrict__ Whi,
                           uint4* __restrict__ Wlo, int KT) {
  int e = blockIdx.x * 256 + threadIdx.x;
  int lane = e & 63;
  int kt = (e >> 6) % KT;
  int blk = e / (64 * KT);
  int cf = lane & 15;
  int g = cf & 3, ul = cf >> 2;
  int col = g * 1024 + blk * 4 + ul;
  int kbase = kt * 32 + ((lane >> 4) & 3) * 4;
  unsigned hi[8], lo[8];
#pragma unroll
  for (int j = 0; j < 8; ++j) {
    int k = kbase + (j & 3) + 16 * (j >> 2);
    float f = W[(size_t)k * 4096 + col];
    unsigned short h = f2bf(f);
    hi[j] = h;
    lo[j] = f2bf(f - bf2f(h));
  }
  uint4 vh, vl;
  vh.x = hi[0] | (hi[1] << 16); vh.y = hi[2] | (hi[3] << 16);
  vh.z = hi[4] | (hi[5] << 16); vh.w = hi[6] | (hi[7] << 16);
  vl.x = lo[0] | (lo[1] << 16); vl.y = lo[2] | (lo[3] << 16);
  vl.z = lo[4] | (lo[5] << 16); vl.w = lo[6] | (lo[7] << 16);
  Whi[e] = vh;
  Wlo[e] = vl;
}

// ======================= persistent kernel =================================

__global__ __launch_bounds__(THREADS, 1) void lstm_persist(
    const int* __restrict__ ib,
    const float* __restrict__ bias0, const float* __restrict__ bias1,
    const uint4* __restrict__ Whi0g, const uint4* __restrict__ Wlo0g,
    const uint4* __restrict__ Whi1g, const uint4* __restrict__ Wlo1g,
    const unsigned short* __restrict__ embHi, const unsigned short* __restrict__ embLo,
    const int* __restrict__ perm, const int* __restrict__ lenS,
    const int* __restrict__ ncnt,
    unsigned short* hg0hi, unsigned short* hg0lo,   // [3][128][1024]
    unsigned short* hg1hi, unsigned short* hg1lo,
    unsigned short* rep,                            // [8][4][128][1024]
    int* ctr, float* __restrict__ out) {
  const int bid = blockIdx.x;
  const int tid = threadIdx.x;
  const int w = tid >> 6;                 // wave 0..7 -> rows w*16..+15
  const int lane = tid & 63;
  const int lr = lane & 15;
  const int lg4 = ((lane >> 4) & 3) * 4;
  const int arow = w * 16 + lr;           // GEMM A row for this lane
  const int srow = tid >> 2;              // cell row 0..127
  const int cu = tid & 3;                 // cell unit 0..3
  const int ug = bid * 4 + cu;            // global unit
  const int permA = perm[arow];
  const int cperm = perm[srow];
  const int clen = lenS[srow];

  __shared__ uint4 Wh0[KT0B * 64];        // 40 KB
  __shared__ uint4 Wh1[KT1B * 64];        // 64 KB
  __shared__ float zb[2][128][17];        // 17 KB
  __shared__ int s_x, s_rk, s_R, s_NX, s_ok;

  // ---- one-time: W-hi slabs -> LDS ----
  {
    const uint4* s0 = Whi0g + (size_t)bid * (KT0B * 64);
    for (int i = tid; i < KT0B * 64; i += THREADS) Wh0[i] = s0[i];
    const uint4* s1 = Whi1g + (size_t)bid * (KT1B * 64);
    for (int i = tid; i < KT1B * 64; i += THREADS) Wh1[i] = s1[i];
  }

  float bz0[4], bz1[4];
#pragma unroll
  for (int g = 0; g < 4; ++g) {
    bz0[g] = bias0[g * 1024 + ug];
    bz1[g] = bias1[g * 1024 + ug];
  }
  float c0r = 0.0f, c1r = 0.0f;           // cell states in registers

  // ---- bootstrap: XCD registration + first global sync (atomics, once) ----
  if (tid == 0) {
    s_ok = 1;
    int x = xcc_id();
    s_x = x;
    s_rk = atomicAdd(&ctr[F_CREG + x * 16], 1);
    vm_wait0();
    atomicAdd(&ctr[F_BOOT], 1);
    if (!spin_ge(&ctr[F_BOOT], NBLK)) s_ok = 0;
    int nx = 0, Rv = 1;
    for (int i = 0; i < 8; ++i) {
      int r = load_i32_llc(&ctr[F_CREG + i * 16]);
      if (r > 0) nx++;
      if (i == s_x) Rv = r;
    }
    s_R = Rv;
    s_NX = nx;
  }
  __syncthreads();
  const int xcd = s_x, rk = s_rk, R = s_R;
  (void)s_NX;
  if (!s_ok) return;

  unsigned short* repB = rep + (size_t)xcd * 4 * HP;
  const unsigned short* rh0hi = repB;
  const unsigned short* rh0lo = repB + HP;
  const unsigned short* rh1hi = repB + 2 * HP;
  const unsigned short* rh1lo = repB + 3 * HP;

  // distribution role (fixed per thread): plane pr, 16B chunk ch
  const int pr = tid >> 7;                // 0..3: h0hi,h0lo,h1hi,h1lo
  const int ch = (tid & 127) * 8;         // u16 offset (16B chunk)
  const unsigned short* spBase =
      (pr == 0) ? hg0hi : (pr == 1) ? hg0lo : (pr == 2) ? hg1hi : hg1lo;
  unsigned short* dp = repB + pr * HP;
  const uint4* wl0g = Wlo0g + (size_t)bid * (KT0B * 64) + lane;
  const uint4* wl1g = Wlo1g + (size_t)bid * (KT1B * 64) + lane;

  for (int p = 0; p < NPH; ++p) {
    // ---- distribute h0(p-1), h1(p-2) planes into this XCD's replica ----
    {
      const int ncopy = ncnt[p == 0 ? 0 : p - 1];
      const int par = (pr < 2) ? (p + 2) % 3 : (p + 1) % 3;
      const unsigned short* sp = spBase + (size_t)par * HP;
      for (int rb = rk; rb < ncopy; rb += 4 * R) {
        const int r1 = rb + R, r2 = rb + 2 * R, r3 = rb + 3 * R;
        uint4 v0, v1, v2, v3;
        v0 = llc_load_issue((const unsigned*)(sp + rb * 1024 + ch));
        if (r1 < ncopy) v1 = llc_load_issue((const unsigned*)(sp + r1 * 1024 + ch));
        if (r2 < ncopy) v2 = llc_load_issue((const unsigned*)(sp + r2 * 1024 + ch));
        if (r3 < ncopy) v3 = llc_load_issue((const unsigned*)(sp + r3 * 1024 + ch));
        vm_wait0();
        *(uint4*)(dp + rb * 1024 + ch) = v0;
        if (r1 < ncopy) *(uint4*)(dp + r1 * 1024 + ch) = v1;
        if (r2 < ncopy) *(uint4*)(dp + r2 * 1024 + ch) = v2;
        if (r3 < ncopy) *(uint4*)(dp + r3 * 1024 + ch) = v3;
      }
    }
    __syncthreads();                       // drains vmem (compiler waitcnt)
    // ---- XCD barrier (flag-based) ----
    if (tid == 0) store_u32_llc((unsigned*)&ctr[F_XARR + xcd * 32 + rk], p + 1);
    if (rk == 0 && tid < 32 && tid < R) {
      if (!spin_ge(&ctr[F_XARR + xcd * 32 + tid], p + 1)) s_ok = 0;
    }
    __syncthreads();
    if (rk == 0 && tid == 0) store_u32_llc((unsigned*)&ctr[F_XGO + xcd * 16], p + 1);
    if (tid == 0) {
      if (!spin_ge(&ctr[F_XGO + xcd * 16], p + 1)) s_ok = 0;
    }
    __syncthreads();
    if (!s_ok) break;
    inv_l1();                              // fresh L1 view of replica

    const int nact0 = (p < 512) ? ncnt[p] : 0;
    const int nact1 = (p >= 1) ? ncnt[p - 1] : 0;
    const bool doL0 = (p < 512) && (w * 16 < nact0);
    const bool doL1 = (p >= 1) && (w * 16 < nact1);

    f32x4 acc0 = (f32x4){0.f, 0.f, 0.f, 0.f};
    f32x4 acc1 = (f32x4){0.f, 0.f, 0.f, 0.f};

    // ---- loop1: kt 0..7 (x part, L0 only) ----
    if (doL0) {
      const int tok = ib[(size_t)permA * 512 + p];
      const unsigned short* eh = embHi + tok * 256;
      const unsigned short* el = embLo + tok * 256;
#pragma unroll 4
      for (int kt = 0; kt < 8; ++kt) {
        const int kb = kt * 32 + lg4;
        const bf16x8 ah = frag2(eh + kb), al = frag2(el + kb);
        const bf16x8 bh = asbf(Wh0[kt * 64 + lane]);
        const bf16x8 bl = asbf(wl0g[kt * 64]);
        MFMA3(acc0, ah, al, bh, bl)
      }
    }
    // ---- loop2: h0 part (L0 kt 8..39 / L1 kt 0..31) ----
    {
      const unsigned short* hh = rh0hi + arow * 1024;
      const unsigned short* hl = rh0lo + arow * 1024;
      if (doL0 && doL1) {
#pragma unroll 4
        for (int q = 0; q < 32; ++q) {
          const int kb = q * 32 + lg4;
          const bf16x8 ah = frag2(hh + kb), al = frag2(hl + kb);
          const bf16x8 b0h = asbf(Wh0[(q + 8) * 64 + lane]);
          const bf16x8 b0l = asbf(wl0g[(q + 8) * 64]);
          const bf16x8 b1h = asbf(Wh1[q * 64 + lane]);
          const bf16x8 b1l = asbf(wl1g[q * 64]);
          MFMA3(acc0, ah, al, b0h, b0l)
          MFMA3(acc1, ah, al, b1h, b1l)
        }
      } else if (doL0) {
#pragma unroll 4
        for (int q = 0; q < 32; ++q) {
          const int kb = q * 32 + lg4;
          const bf16x8 ah = frag2(hh + kb), al = frag2(hl + kb);
          const bf16x8 b0h = asbf(Wh0[(q + 8) * 64 + lane]);
          const bf16x8 b0l = asbf(wl0g[(q + 8) * 64]);
          MFMA3(acc0, ah, al, b0h, b0l)
        }
      } else if (doL1) {
#pragma unroll 4
        for (int q = 0; q < 32; ++q) {
          const int kb = q * 32 + lg4;
          const bf16x8 ah = frag2(hh + kb), al = frag2(hl + kb);
          const bf16x8 b1h = asbf(Wh1[q * 64 + lane]);
          const bf16x8 b1l = asbf(wl1g[q * 64]);
          MFMA3(acc1, ah, al, b1h, b1l)
        }
      }
    }
    // ---- loop3: h1 part (L1 kt 32..63) ----
    if (doL1) {
      const unsigned short* hh = rh1hi + arow * 1024;
      const unsigned short* hl = rh1lo + arow * 1024;
#pragma unroll 4
      for (int q = 0; q < 32; ++q) {
        const int kb = q * 32 + lg4;
        const bf16x8 ah = frag2(hh + kb), al = frag2(hl + kb);
        const bf16x8 b1h = asbf(Wh1[(q + 32) * 64 + lane]);
        const bf16x8 b1l = asbf(wl1g[(q + 32) * 64]);
        MFMA3(acc1, ah, al, b1h, b1l)
      }
    }

    // ---- z exchange (C/D: row = 4*(l>>4)+reg, col = l&15) ----
    if (doL0) {
#pragma unroll
      for (int rr = 0; rr < 4; ++rr) zb[0][w * 16 + lg4 + rr][lr] = acc0[rr];
    }
    if (doL1) {
#pragma unroll
      for (int rr = 0; rr < 4; ++rr) zb[1][w * 16 + lg4 + rr][lr] = acc1[rr];
    }
    __syncthreads();

    // ---- fused cells (thread = row x unit), c in registers ----
    if (p < 512 && p < clen) {            // L0, t = p
      const float zi = zb[0][srow][cu * 4 + 0] + bz0[0];
      const float zj = zb[0][srow][cu * 4 + 1] + bz0[1];
      const float zf = zb[0][srow][cu * 4 + 2] + bz0[2];
      const float zo = zb[0][srow][cu * 4 + 3] + bz0[3];
      const float nc = c0r * sigm(zf + 1.0f) + sigm(zi) * tanh_f(zj);
      const float nh = tanh_f(nc) * sigm(zo);
      c0r = nc;
      const unsigned short hh = f2bf(nh);
      const unsigned short hl = f2bf(nh - bf2f(hh));
      const size_t idx = (size_t)(p % 3) * HP + srow * 1024 + ug;
      store_u16_llc(&hg0hi[idx], hh);
      store_u16_llc(&hg0lo[idx], hl);
    }
    if (p >= 1 && (p - 1) < clen) {       // L1, t = p-1
      const float zi = zb[1][srow][cu * 4 + 0] + bz1[0];
      const float zj = zb[1][srow][cu * 4 + 1] + bz1[1];
      const float zf = zb[1][srow][cu * 4 + 2] + bz1[2];
      const float zo = zb[1][srow][cu * 4 + 3] + bz1[3];
      const float nc = c1r * sigm(zf + 1.0f) + sigm(zi) * tanh_f(zj);
      const float nh = tanh_f(nc) * sigm(zo);
      c1r = nc;
      const unsigned short hh = f2bf(nh);
      const unsigned short hl = f2bf(nh - bf2f(hh));
      const size_t idx = (size_t)((p + 2) % 3) * HP + srow * 1024 + ug;
      store_u16_llc(&hg1hi[idx], hh);
      store_u16_llc(&hg1lo[idx], hl);
      if (p == clen) {}                   // (unreachable marker)
      if (p - 1 == clen - 1) out[(size_t)cperm * 1024 + ug] = nh;
    }

    // ---- global barrier (flag-based) ----
    __syncthreads();                      // drains all waves' vmem
    if (tid == 0) store_u32_llc((unsigned*)&ctr[F_ARR + bid], p + 1);
    if (bid == 0) {
      if (tid < 256) {
        if (!spin_ge(&ctr[F_ARR + tid], p + 1)) s_ok = 0;
      }
      __syncthreads();
      if (tid == 0) store_u32_llc((unsigned*)&ctr[F_GO], p + 1);
    }
    if (tid == 0) {
      if (!spin_ge(&ctr[F_GO], p + 1)) s_ok = 0;
    }
    __syncthreads();
    if (!s_ok) break;
  }
}

// ======================= host launch =======================================

extern "C" void kernel_launch(void* const* d_in, const int* in_sizes, int n_in,
                              void* d_out, int out_size, void* d_ws, size_t ws_size,
                              hipStream_t stream) {
  const int*   ib   = (const int*)d_in[0];
  const int*   lens = (const int*)d_in[1];
  const float* emb  = (const float*)d_in[2];
  const float* W0   = (const float*)d_in[3];
  const float* b0   = (const float*)d_in[4];
  const float* W1   = (const float*)d_in[5];
  const float* b1   = (const float*)d_in[6];
  (void)in_sizes; (void)n_in; (void)out_size; (void)ws_size;

  char* ws = (char*)d_ws;
  size_t off = 0;
  auto alloc = [&](size_t bytes) { char* q = ws + off; off += (bytes + 255) & ~(size_t)255; return q; };

  int*            ctr   = (int*)alloc(4096);
  unsigned short* hg0hi = (unsigned short*)alloc((size_t)3 * HP * 2);
  unsigned short* hg0lo = (unsigned short*)alloc((size_t)3 * HP * 2);
  unsigned short* hg1hi = (unsigned short*)alloc((size_t)3 * HP * 2);
  unsigned short* hg1lo = (unsigned short*)alloc((size_t)3 * HP * 2);
  const size_t zero_bytes = off;          // ctr + h planes
  unsigned short* embHi = (unsigned short*)alloc(128 * 256 * 2);
  unsigned short* embLo = (unsigned short*)alloc(128 * 256 * 2);
  int*            perm  = (int*)alloc(4096);   // perm[128], lenS[128], ncnt[512]
  int*            lenS  = perm + 128;
  int*            ncnt  = perm + 256;
  unsigned short* rep   = (unsigned short*)alloc((size_t)8 * 4 * HP * 2);
  uint4*          Whi0  = (uint4*)alloc((size_t)NBLK * KT0B * 64 * 16);
  uint4*          Wlo0  = (uint4*)alloc((size_t)NBLK * KT0B * 64 * 16);
  uint4*          Whi1  = (uint4*)alloc((size_t)NBLK * KT1B * 64 * 16);
  uint4*          Wlo1  = (uint4*)alloc((size_t)NBLK * KT1B * 64 * 16);

  hipMemsetAsync(d_ws, 0, zero_bytes, stream);
  prep_sort<<<1, 512, 0, stream>>>(lens, perm, lenS, ncnt);
  prep_emb<<<128, 256, 0, stream>>>(emb, embHi, embLo);
  prep_wslab<<<(NBLK * KT0B * 64) / 256, 256, 0, stream>>>(W0, Whi0, Wlo0, KT0B);
  prep_wslab<<<(NBLK * KT1B * 64) / 256, 256, 0, stream>>>(W1, Whi1, Wlo1, KT1B);
  lstm_persist<<<NBLK, THREADS, 0, stream>>>(
      ib, b0, b1, Whi0, Wlo0, Whi1, Wlo1, embHi, embLo,
      perm, lenS, ncnt, hg0hi, hg0lo, hg1hi, hg1lo, rep, ctr, (float*)d_out);
}